// Round 1
// baseline (111.575 us; speedup 1.0000x reference)
//
#include <hip/hip_runtime.h>
#include <hip/hip_bf16.h>
#include <math.h>

// Problem constants (B=4096, D=128, T=0.5 -> 1/T = 2)
#define BB       4096
#define N2       8192          // 2B rows of z
#define DIMS     128
#define ROWS_PER_BLOCK 64      // 4 waves x 16 rows
#define COL_SPLIT 4
#define COLS_PER_BLOCK (N2 / COL_SPLIT)   // 2048
#define CHUNK    64            // columns staged in LDS per iteration
#define LDS_PAD  8             // bf16 elements of padding per row (breaks 256B-stride bank conflicts)
#define LDS_ROWW (DIMS + LDS_PAD)  // 136 shorts = 272 B, 16B-aligned

typedef __attribute__((ext_vector_type(8))) short short8;   // 8 x bf16 (4 VGPRs)
typedef __attribute__((ext_vector_type(4))) float float4v;  // MFMA C/D

// ---------------------------------------------------------------------------
// Kernel 1: normalize rows (fp32), compute positives (fp32), write z as bf16.
// One wave per row-pair r: handles emb_i[r] -> z[r] and emb_j[r] -> z[r+B].
// ---------------------------------------------------------------------------
__global__ __launch_bounds__(256) void norm_kernel(
    const float* __restrict__ emb_i, const float* __restrict__ emb_j,
    __hip_bfloat16* __restrict__ z, float* __restrict__ pos) {
  int gw   = (blockIdx.x * blockDim.x + threadIdx.x) >> 6;  // global wave id = row pair
  int lane = threadIdx.x & 63;
  if (gw >= BB) return;

  const float2* ei = (const float2*)(emb_i + (size_t)gw * DIMS);
  const float2* ej = (const float2*)(emb_j + (size_t)gw * DIMS);
  float2 a = ei[lane];
  float2 b = ej[lane];

  float sa = a.x * a.x + a.y * a.y;
  float sb = b.x * b.x + b.y * b.y;
  #pragma unroll
  for (int m = 32; m; m >>= 1) {
    sa += __shfl_xor(sa, m, 64);
    sb += __shfl_xor(sb, m, 64);
  }
  float inva = 1.0f / fmaxf(sqrtf(sa), 1e-12f);
  float invb = 1.0f / fmaxf(sqrtf(sb), 1e-12f);

  float zi0 = a.x * inva, zi1 = a.y * inva;
  float zj0 = b.x * invb, zj1 = b.y * invb;

  // positive pair dot in fp32 (matches reference's fp32 einsum path)
  float p = zi0 * zj0 + zi1 * zj1;
  #pragma unroll
  for (int m = 32; m; m >>= 1) p += __shfl_xor(p, m, 64);
  if (lane == 0) pos[gw] = p;

  __hip_bfloat162* zr_i = (__hip_bfloat162*)(z + (size_t)gw * DIMS);
  __hip_bfloat162* zr_j = (__hip_bfloat162*)(z + (size_t)(gw + BB) * DIMS);
  __hip_bfloat162 vi, vj;
  vi.x = __float2bfloat16(zi0); vi.y = __float2bfloat16(zi1);
  vj.x = __float2bfloat16(zj0); vj.y = __float2bfloat16(zj1);
  zr_i[lane] = vi;
  zr_j[lane] = vj;
}

// ---------------------------------------------------------------------------
// Kernel 2: fused sim-GEMM + exp + row-sum.
// Block = 256 threads (4 waves). Block owns 64 rows x 2048 columns.
// Each wave owns 16 rows; A-fragments (16 rows x 128 K) live in registers for
// the whole column loop. 64-column tiles of z staged in LDS (shared by waves).
// MFMA 16x16x32 bf16: A[m=lane&15][k=quad*8+j], B[k=quad*8+j][n=lane&15],
// C: col=lane&15, row=quad*4+reg (HW-verified layouts).
// ---------------------------------------------------------------------------
__global__ __launch_bounds__(256, 2) void simloss_main(
    const __hip_bfloat16* __restrict__ z, float* __restrict__ denom) {
  const int blk     = blockIdx.x;
  const int rowBlk  = blk >> 2;        // 0..127
  const int colBlk  = blk & 3;         // 0..3
  const int rowBase = rowBlk * ROWS_PER_BLOCK;
  const int colBase0 = colBlk * COLS_PER_BLOCK;
  const int tid  = threadIdx.x;
  const int wave = tid >> 6;
  const int lane = tid & 63;
  const int lr   = lane & 15;          // A-row / B-col / C-col within tile
  const int quad = lane >> 4;          // k-group for A/B, row-group for C

  __shared__ short lds[CHUNK * LDS_ROWW];  // 64 x 136 bf16 = 17408 B

  const ushort* zp = (const ushort*)z;

  // Preload A fragments: row = rowBase + wave*16 + lr, k = kk*32 + quad*8 + j
  short8 afrag[4];
  {
    const int arow = rowBase + wave * 16 + lr;
    const short8* ap = (const short8*)(zp + (size_t)arow * DIMS + quad * 8);
    afrag[0] = ap[0];
    afrag[1] = ap[4];   // +32 shorts
    afrag[2] = ap[8];
    afrag[3] = ap[12];
  }

  float rowsum[4] = {0.0f, 0.0f, 0.0f, 0.0f};
  const int myRowBase = rowBase + wave * 16 + quad * 4;  // + reg -> global row

  for (int cc = 0; cc < COLS_PER_BLOCK; cc += CHUNK) {
    const int colBase = colBase0 + cc;

    __syncthreads();  // previous iteration's LDS reads done
    {
      // Stage 64 cols x 128 dims of z: 1024 short8 total, 4 per thread.
      const short8* src = (const short8*)(zp + (size_t)colBase * DIMS);
      #pragma unroll
      for (int i = 0; i < 4; i++) {
        int idx  = tid + 256 * i;        // linear short8 index
        int row  = idx >> 4;             // 16 short8 per logical row
        int col8 = idx & 15;
        *(short8*)&lds[row * LDS_ROWW + col8 * 8] = src[idx];
      }
    }
    __syncthreads();

    #pragma unroll
    for (int t = 0; t < 4; t++) {  // 4 column tiles of 16
      const short8* bp = (const short8*)&lds[(t * 16 + lr) * LDS_ROWW + quad * 8];
      float4v acc = {0.0f, 0.0f, 0.0f, 0.0f};
      acc = __builtin_amdgcn_mfma_f32_16x16x32_bf16(afrag[0], bp[0],  acc, 0, 0, 0);
      acc = __builtin_amdgcn_mfma_f32_16x16x32_bf16(afrag[1], bp[4],  acc, 0, 0, 0);
      acc = __builtin_amdgcn_mfma_f32_16x16x32_bf16(afrag[2], bp[8],  acc, 0, 0, 0);
      acc = __builtin_amdgcn_mfma_f32_16x16x32_bf16(afrag[3], bp[12], acc, 0, 0, 0);

      const int gc = colBase + t * 16 + lr;  // global column of this lane's accs
      #pragma unroll
      for (int r = 0; r < 4; r++) {
        const int gr = myRowBase + r;
        // exp(sim/T) = exp(2*sim) = exp2(sim * 2*log2(e))
        float e = exp2f(acc[r] * 2.8853900817779268f);
        rowsum[r] += (gr != gc) ? e : 0.0f;  // exact diagonal skip
      }
    }
  }

  // Reduce partial row sums across the 16 lanes of each quad (xor bits 0..3).
  #pragma unroll
  for (int m = 1; m < 16; m <<= 1) {
    #pragma unroll
    for (int r = 0; r < 4; r++) rowsum[r] += __shfl_xor(rowsum[r], m, 64);
  }
  if (lr == 0) {
    #pragma unroll
    for (int r = 0; r < 4; r++) atomicAdd(&denom[myRowBase + r], rowsum[r]);
  }
}

// ---------------------------------------------------------------------------
// Kernel 3: loss = (1/2B) * sum_r [ log(denom[r]) - 2*pos[r mod B] ]
// Single block; double accumulation (fp32 naive sum of 8192 ~9-magnitude
// terms would random-walk to ~0.1 absolute error, too close to threshold).
// ---------------------------------------------------------------------------
__global__ __launch_bounds__(256) void finalize(
    const float* __restrict__ denom, const float* __restrict__ pos,
    float* __restrict__ out) {
  __shared__ double sred[256];
  int tid = threadIdx.x;
  double acc = 0.0;
  for (int r = tid; r < N2; r += 256) {
    acc += (double)(logf(denom[r]) - 2.0f * pos[r & (BB - 1)]);
  }
  sred[tid] = acc;
  __syncthreads();
  for (int s = 128; s; s >>= 1) {
    if (tid < s) sred[tid] += sred[tid + s];
    __syncthreads();
  }
  if (tid == 0) out[0] = (float)(sred[0] / (double)N2);
}

// ---------------------------------------------------------------------------
extern "C" void kernel_launch(void* const* d_in, const int* in_sizes, int n_in,
                              void* d_out, int out_size, void* d_ws, size_t ws_size,
                              hipStream_t stream) {
  const float* emb_i = (const float*)d_in[0];
  const float* emb_j = (const float*)d_in[1];

  // workspace layout
  __hip_bfloat16* z = (__hip_bfloat16*)d_ws;                         // 8192*128*2 = 2 MiB
  float* pos   = (float*)((char*)d_ws + (size_t)N2 * DIMS * 2);      // 4096 f32
  float* denom = (float*)((char*)pos + BB * sizeof(float));          // 8192 f32

  hipMemsetAsync(denom, 0, N2 * sizeof(float), stream);
  norm_kernel<<<BB / 4, 256, 0, stream>>>(emb_i, emb_j, z, pos);
  simloss_main<<<(N2 / ROWS_PER_BLOCK) * COL_SPLIT, 256, 0, stream>>>(z, denom);
  finalize<<<1, 256, 0, stream>>>(denom, pos, (float*)d_out);
}

// Round 2
// 92.012 us; speedup vs baseline: 1.2126x; 1.2126x over previous
//
#include <hip/hip_runtime.h>
#include <hip/hip_bf16.h>
#include <math.h>

// Problem constants (B=4096, D=128, T=0.5 -> 1/T = 2)
#define BB       4096
#define N2       8192          // 2B rows of z
#define DIMS     128
#define WAVES    4
#define ROWTILES 4             // 16-row MFMA tiles per wave
#define ROWS_PER_WAVE   64     // ROWTILES * 16
#define ROWS_PER_BLOCK  256    // WAVES * ROWS_PER_WAVE
#define COL_SPLIT       16
#define COLS_PER_BLOCK  (N2 / COL_SPLIT)   // 512
#define CHUNK    64            // columns staged in LDS per iteration
#define LDS_PAD  8             // bf16 pad per row: breaks 256B-stride 16B-group conflicts
#define LDS_ROWW (DIMS + LDS_PAD)  // 136 shorts = 272 B

// z rows are pre-scaled by ZSCALE so the MFMA dot directly yields
// sim * 2*log2(e), i.e. exp(sim/T) = exp2(acc). ZSCALE^2 = 2.8853900818.
#define ZSCALE   1.6986436f
// diagonal term exp(2 * |z_r|^2) ~= exp(2) — subtracted in finalize.
// bf16 rounding perturbs it by <=~0.12 vs a ~8200 denominator: negligible.
#define DIAG_E2  7.38905609893065f

typedef __attribute__((ext_vector_type(8))) short short8;   // 8 x bf16 (4 VGPRs)
typedef __attribute__((ext_vector_type(4))) float float4v;  // MFMA C/D

// ---------------------------------------------------------------------------
// Kernel 1: normalize rows (fp32), compute positives (fp32), write z as
// bf16 scaled by ZSCALE. Also zeroes the denom accumulators (blocks 0..31).
// One wave per row-pair r: handles emb_i[r] -> z[r] and emb_j[r] -> z[r+B].
// ---------------------------------------------------------------------------
__global__ __launch_bounds__(256) void norm_kernel(
    const float* __restrict__ emb_i, const float* __restrict__ emb_j,
    __hip_bfloat16* __restrict__ z, float* __restrict__ pos,
    float* __restrict__ denom) {
  if (blockIdx.x < N2 / 256) denom[blockIdx.x * 256 + threadIdx.x] = 0.0f;

  int gw   = (blockIdx.x * blockDim.x + threadIdx.x) >> 6;  // row pair
  int lane = threadIdx.x & 63;
  if (gw >= BB) return;

  const float2* ei = (const float2*)(emb_i + (size_t)gw * DIMS);
  const float2* ej = (const float2*)(emb_j + (size_t)gw * DIMS);
  float2 a = ei[lane];
  float2 b = ej[lane];

  float sa = a.x * a.x + a.y * a.y;
  float sb = b.x * b.x + b.y * b.y;
  #pragma unroll
  for (int m = 32; m; m >>= 1) {
    sa += __shfl_xor(sa, m, 64);
    sb += __shfl_xor(sb, m, 64);
  }
  float inva = 1.0f / fmaxf(sqrtf(sa), 1e-12f);
  float invb = 1.0f / fmaxf(sqrtf(sb), 1e-12f);

  float zi0 = a.x * inva, zi1 = a.y * inva;
  float zj0 = b.x * invb, zj1 = b.y * invb;

  // positive pair dot in unscaled fp32 (matches reference's fp32 einsum)
  float p = zi0 * zj0 + zi1 * zj1;
  #pragma unroll
  for (int m = 32; m; m >>= 1) p += __shfl_xor(p, m, 64);
  if (lane == 0) pos[gw] = p;

  __hip_bfloat162* zr_i = (__hip_bfloat162*)(z + (size_t)gw * DIMS);
  __hip_bfloat162* zr_j = (__hip_bfloat162*)(z + (size_t)(gw + BB) * DIMS);
  __hip_bfloat162 vi, vj;
  vi.x = __float2bfloat16(zi0 * ZSCALE); vi.y = __float2bfloat16(zi1 * ZSCALE);
  vj.x = __float2bfloat16(zj0 * ZSCALE); vj.y = __float2bfloat16(zj1 * ZSCALE);
  zr_i[lane] = vi;
  zr_j[lane] = vj;
}

// ---------------------------------------------------------------------------
// Kernel 2: fused sim-GEMM + exp2 + row-sum.
// Block = 256 threads (4 waves). Block owns 256 rows x 512 columns.
// Each wave owns 64 rows: 16 A-fragments (64 rows x 128 K) pinned in VGPRs
// for the whole kernel, so each B-fragment ds_read_b128 feeds 4 MFMAs
// (4x less LDS traffic than 1:1). 64-col chunks of z staged in LDS.
// MFMA 16x16x32 bf16: A[m=lane&15][k=quad*8+j], B[k=quad*8+j][n=lane&15],
// C: col=lane&15, row=quad*4+reg (HW-verified layouts).
// Diagonal terms are INCLUDED here and subtracted in finalize.
// ---------------------------------------------------------------------------
__global__ __launch_bounds__(256, 2) void simloss_main(
    const __hip_bfloat16* __restrict__ z, float* __restrict__ denom) {
  const int blk      = blockIdx.x;
  const int rowBlk   = blk >> 4;       // 0..31
  const int colBlk   = blk & 15;       // 0..15
  const int rowBase  = rowBlk * ROWS_PER_BLOCK;
  const int colBase0 = colBlk * COLS_PER_BLOCK;
  const int tid  = threadIdx.x;
  const int wave = tid >> 6;
  const int lane = tid & 63;
  const int lr   = lane & 15;          // A-row / B-col / C-col within tile
  const int quad = lane >> 4;          // k-group for A/B, row-group for C

  __shared__ short lds[CHUNK * LDS_ROWW];  // 64 x 136 bf16 = 17408 B

  const ushort* zp = (const ushort*)z;

  // Preload A fragments: row = rowBase + wave*64 + rt*16 + lr, k = kk*32 + quad*8 + j
  short8 afrag[ROWTILES][4];
  #pragma unroll
  for (int rt = 0; rt < ROWTILES; rt++) {
    const int arow = rowBase + wave * ROWS_PER_WAVE + rt * 16 + lr;
    const short8* ap = (const short8*)(zp + (size_t)arow * DIMS + quad * 8);
    afrag[rt][0] = ap[0];
    afrag[rt][1] = ap[4];   // +32 shorts
    afrag[rt][2] = ap[8];
    afrag[rt][3] = ap[12];
  }

  float rowsum[ROWTILES][4];
  #pragma unroll
  for (int rt = 0; rt < ROWTILES; rt++)
    #pragma unroll
    for (int r = 0; r < 4; r++) rowsum[rt][r] = 0.0f;

  for (int cc = 0; cc < COLS_PER_BLOCK; cc += CHUNK) {
    const int colBase = colBase0 + cc;

    __syncthreads();  // previous iteration's LDS reads done
    {
      // Stage 64 cols x 128 dims of z: 1024 short8 total, 4 per thread.
      const short8* src = (const short8*)(zp + (size_t)colBase * DIMS);
      #pragma unroll
      for (int i = 0; i < 4; i++) {
        int idx  = tid + 256 * i;        // linear short8 index
        int row  = idx >> 4;             // 16 short8 per logical row
        int col8 = idx & 15;
        *(short8*)&lds[row * LDS_ROWW + col8 * 8] = src[idx];
      }
    }
    __syncthreads();

    #pragma unroll
    for (int t = 0; t < 4; t++) {  // 4 column tiles of 16
      const short8* bp = (const short8*)&lds[(t * 16 + lr) * LDS_ROWW + quad * 8];
      short8 b0 = bp[0];
      short8 b1 = bp[4];
      short8 b2 = bp[8];
      short8 b3 = bp[12];
      #pragma unroll
      for (int rt = 0; rt < ROWTILES; rt++) {
        float4v acc = {0.0f, 0.0f, 0.0f, 0.0f};
        acc = __builtin_amdgcn_mfma_f32_16x16x32_bf16(afrag[rt][0], b0, acc, 0, 0, 0);
        acc = __builtin_amdgcn_mfma_f32_16x16x32_bf16(afrag[rt][1], b1, acc, 0, 0, 0);
        acc = __builtin_amdgcn_mfma_f32_16x16x32_bf16(afrag[rt][2], b2, acc, 0, 0, 0);
        acc = __builtin_amdgcn_mfma_f32_16x16x32_bf16(afrag[rt][3], b3, acc, 0, 0, 0);
        // exp(sim/T) = exp2(acc) thanks to ZSCALE pre-scaling.
        #pragma unroll
        for (int r = 0; r < 4; r++)
          rowsum[rt][r] += __builtin_amdgcn_exp2f(acc[r]);
      }
    }
  }

  // Reduce partial row sums across the 16 lanes of each quad (xor bits 0..3).
  #pragma unroll
  for (int m = 1; m < 16; m <<= 1) {
    #pragma unroll
    for (int rt = 0; rt < ROWTILES; rt++)
      #pragma unroll
      for (int r = 0; r < 4; r++)
        rowsum[rt][r] += __shfl_xor(rowsum[rt][r], m, 64);
  }
  if (lr == 0) {
    #pragma unroll
    for (int rt = 0; rt < ROWTILES; rt++)
      #pragma unroll
      for (int r = 0; r < 4; r++)
        atomicAdd(&denom[rowBase + wave * ROWS_PER_WAVE + rt * 16 + quad * 4 + r],
                  rowsum[rt][r]);
  }
}

// ---------------------------------------------------------------------------
// Kernel 3: loss = (1/2B) * sum_r [ log(denom[r] - e^2) - 2*pos[r mod B] ]
// Single block; double accumulation (fp32 naive sum of 8192 ~9-magnitude
// terms would random-walk too close to the threshold).
// ---------------------------------------------------------------------------
__global__ __launch_bounds__(256) void finalize(
    const float* __restrict__ denom, const float* __restrict__ pos,
    float* __restrict__ out) {
  __shared__ double sred[256];
  int tid = threadIdx.x;
  double acc = 0.0;
  for (int r = tid; r < N2; r += 256) {
    acc += (double)(logf(denom[r] - DIAG_E2) - 2.0f * pos[r & (BB - 1)]);
  }
  sred[tid] = acc;
  __syncthreads();
  for (int s = 128; s; s >>= 1) {
    if (tid < s) sred[tid] += sred[tid + s];
    __syncthreads();
  }
  if (tid == 0) out[0] = (float)(sred[0] / (double)N2);
}

// ---------------------------------------------------------------------------
extern "C" void kernel_launch(void* const* d_in, const int* in_sizes, int n_in,
                              void* d_out, int out_size, void* d_ws, size_t ws_size,
                              hipStream_t stream) {
  const float* emb_i = (const float*)d_in[0];
  const float* emb_j = (const float*)d_in[1];

  // workspace layout
  __hip_bfloat16* z = (__hip_bfloat16*)d_ws;                         // 8192*128*2 = 2 MiB
  float* pos   = (float*)((char*)d_ws + (size_t)N2 * DIMS * 2);      // 4096 f32
  float* denom = (float*)((char*)pos + BB * sizeof(float));          // 8192 f32

  norm_kernel<<<BB / 4, 256, 0, stream>>>(emb_i, emb_j, z, pos, denom);
  simloss_main<<<(N2 / ROWS_PER_BLOCK) * COL_SPLIT, 256, 0, stream>>>(z, denom);
  finalize<<<1, 256, 0, stream>>>(denom, pos, (float*)d_out);
}